// Round 9
// baseline (229.973 us; speedup 1.0000x reference)
//
#include <hip/hip_runtime.h>

typedef __attribute__((ext_vector_type(8))) short bf16x8;
typedef __attribute__((ext_vector_type(4))) short short4v;
typedef __attribute__((ext_vector_type(4))) float f32x4;
typedef __attribute__((ext_vector_type(2))) unsigned u32x2;

#define MFMA16x16x32(a, b, c) __builtin_amdgcn_mfma_f32_16x16x32_bf16((a), (b), (c), 0, 0, 0)

__device__ __forceinline__ short f2bf(float f) {
    unsigned u = __builtin_bit_cast(unsigned, f);
    u += 0x7FFFu + ((u >> 16) & 1u);   // RNE
    return (short)(u >> 16);
}

// packed fp32x2 -> bf16x2 (RNE): D[15:0]=cvt(S0), D[31:16]=cvt(S1).
__device__ __forceinline__ unsigned cvtpk(float lo, float hi) {
    unsigned r;
    asm("v_cvt_pk_bf16_f32 %0, %1, %2" : "=v"(r) : "v"(lo), "v"(hi));
    return r;
}

// async global->LDS, 16B per lane. LDS dest: wave-uniform base + lane*16 [m104].
__device__ __forceinline__ void gl_lds16(const void* g, void* l) {
    __builtin_amdgcn_global_load_lds((__attribute__((address_space(1))) void*)g,
                                     (__attribute__((address_space(3))) void*)l,
                                     16, 0, 0);
}

// Convert 16 consecutive floats at p into two bf16x8 packs.
__device__ __forceinline__ void cvt16(const float* __restrict__ p, bf16x8& lo, bf16x8& hi) {
    f32x4 a = *(const f32x4*)(p);
    f32x4 b = *(const f32x4*)(p + 4);
    f32x4 c = *(const f32x4*)(p + 8);
    f32x4 d = *(const f32x4*)(p + 12);
#pragma unroll
    for (int i = 0; i < 4; ++i) {
        lo[i]     = f2bf(a[i]);
        lo[i + 4] = f2bf(b[i]);
        hi[i]     = f2bf(c[i]);
        hi[i + 4] = f2bf(d[i]);
    }
}

// ---------------------------------------------------------------------------
// prep: fused {cvt3 (blocks 0..3071)} + {transW4 (blocks 3072..4095)}.
// ---------------------------------------------------------------------------
__global__ __launch_bounds__(256) void prep(const float* __restrict__ q,
                                            const float* __restrict__ k,
                                            const float* __restrict__ v,
                                            const float* __restrict__ w0,
                                            const float* __restrict__ w1,
                                            const float* __restrict__ w2,
                                            const float* __restrict__ w3,
                                            short* __restrict__ y,
                                            short* __restrict__ wt) {
    __shared__ short t[64][80];
    int bid = blockIdx.x, tid = threadIdx.x;
    if (bid < 3072) {
        int sel = bid >> 10;
        const float* x = sel == 0 ? q : (sel == 1 ? k : v);
        short* yy = y + (size_t)sel * (1 << 22);
        int i = ((bid & 1023) * 256 + tid) * 16;
        bf16x8 lo, hi;
        cvt16(x + i, lo, hi);
        *(bf16x8*)(yy + i)     = lo;
        *(bf16x8*)(yy + i + 8) = hi;
        return;
    }
    int tz = bid - 3072;
    int z = tz >> 8, rem = tz & 255, bx = rem & 15, by = rem >> 4;
    const float* W = z == 0 ? w0 : (z == 1 ? w1 : (z == 2 ? w2 : w3));
    short* Wt = wt + (size_t)z * (1 << 20);
    int sr = tid >> 2, sc = (tid & 3) * 16;
    bf16x8 lo, hi;
    cvt16(W + (by * 64 + sr) * 1024 + bx * 64 + sc, lo, hi);
    *(bf16x8*)&t[sr][sc]     = lo;
    *(bf16x8*)&t[sr][sc + 8] = hi;
    __syncthreads();
    bf16x8 o0, o1;
#pragma unroll
    for (int i = 0; i < 8; ++i) {
        o0[i] = t[sc + i][sr];
        o1[i] = t[sc + 8 + i][sr];
    }
    short* dst = Wt + (bx * 64 + sr) * 1024 + by * 64 + sc;
    *(bf16x8*)(dst)     = o0;
    *(bf16x8*)(dst + 8) = o1;
}

// ---------------------------------------------------------------------------
// QKV projection GEMM, 256Mx128N tile, wave 64x64 [this round].
// MODEL (closes on R6 data): R6 was LDS-read-BW-bound — 96 KB ds_read/CU/step
// = 980 cyc @98 B/cyc ≈ measured step; MfmaUtil 16% predicted ≈ 14.5-19%
// measured. Fix = fragment REUSE, not scheduling: wave 64x64 (acc[4][4])
// reads 8 b128/ks for 16 MFMA = 0.25 reads/MFMA (R6: 0.75). Per CU-step now
// LDS 1306 cyc vs MFMA 1034 cyc — balanced.
// Control flow = R6-EXACT (3-buffer, distance-2, counted vmcnt; 2 rounds HW-
// validated; parameter-only change): per step {vmcnt(6) -> raw barrier ->
// stage(t+2) -> ds_read+MFMA(t)}. 6 loads/thread/stage (A:4, B:2).
// LDS 144 KB = 3 x (A 32KB + B 16KB). vmcnt(0) drain added before epilogue
// (in-flight wrap loads at kernel exit).
// T2 slot-XOR swizzle (conflicts=0, R6-verified), T5 setprio.
// Grid 384 = 8 xcd x {bm:2, bn:8, z:3}, z-major in time -> per-XCD working
// set A 1MB + W 2MB = 3MB < 4MB L2.
// Epilogue: z<2 -> RoPE bf16 [BH,S,64]; z=2 -> bf16 V^T [BH,64,S].
// ---------------------------------------------------------------------------
__global__ __launch_bounds__(512) void gemm_qkv(const short* __restrict__ A0,
                                                const short* __restrict__ A1,
                                                const short* __restrict__ A2,
                                                const short* __restrict__ wt,
                                                const float* __restrict__ b0,
                                                const float* __restrict__ b1,
                                                const float* __restrict__ b2,
                                                short* __restrict__ d0,
                                                short* __restrict__ d1,
                                                short* __restrict__ d2,
                                                int zoff) {
    __shared__ short As[3][256 * 64];   // 96 KB
    __shared__ short Bs[3][128 * 64];   // 48 KB
    const int K = 1024;
    int flat = blockIdx.x;
    int xcd = flat & 7, j = flat >> 3;
    int z  = zoff + (j >> 4);
    int r  = j & 15;
    int bm = xcd * 2 + (r & 1);          // [0,16): 2 A-panels per XCD per z
    int bn = r >> 1;                     // [0,8)
    const short* A    = z == 0 ? A0 : (z == 1 ? A1 : A2);
    const short* Bt   = wt + (size_t)z * (1 << 20);
    const float* bias = z == 0 ? b0 : (z == 1 ? b1 : b2);
    short* dst        = z == 0 ? d0 : (z == 1 ? d1 : d2);

    int tid = threadIdx.x;
    int wave = tid >> 6, lane = tid & 63;
    int quad = lane >> 4, l16 = lane & 15;
    int wm = (wave >> 1) * 64;           // 4 M-waves
    int wn = (wave & 1) * 64;            // 2 N-waves
    int swr = l16 & 7;                   // read-side slot swizzle

    f32x4 acc[4][4] = {};

    auto stage = [&](int b, int t) {
        int kb = t * 64;
#pragma unroll
        for (int jj = 0; jj < 4; ++jj) {   // A tile: 256x64 = 2048 16B chunks
            int c = jj * 512 + tid;
            int row = c >> 3, sl = c & 7;
            gl_lds16(A + (bm * 256 + row) * K + kb + ((sl ^ (row & 7)) * 8),
                     &As[b][c * 8]);
        }
#pragma unroll
        for (int jj = 0; jj < 2; ++jj) {   // B tile: 128x64 = 1024 chunks
            int c = jj * 512 + tid;
            int row = c >> 3, sl = c & 7;
            gl_lds16(Bt + (bn * 128 + row) * K + kb + ((sl ^ (row & 7)) * 8),
                     &Bs[b][c * 8]);
        }
    };

    stage(0, 0);                          // prologue: 2 tiles in flight
    stage(1, 1);

    int cur = 0;
    for (int t = 0; t < 16; ++t) {
        asm volatile("s_waitcnt vmcnt(6)" ::: "memory");   // tile t landed
        __builtin_amdgcn_sched_barrier(0);
        __builtin_amdgcn_s_barrier();     // raw: no vmcnt(0) drain
        __builtin_amdgcn_sched_barrier(0);
        int pre = cur >= 1 ? cur - 1 : 2; // (cur+2)%3
        stage(pre, (t + 2) & 15);         // wrap-harmless on last 2 iters
#pragma unroll
        for (int ks = 0; ks < 2; ++ks) {
            bf16x8 bf[4], af[4];
#pragma unroll
            for (int ni = 0; ni < 4; ++ni)
                bf[ni] = *(const bf16x8*)
                    &Bs[cur][(wn + ni * 16 + l16) * 64 + (((ks * 4 + quad) ^ swr) * 8)];
#pragma unroll
            for (int mi = 0; mi < 4; ++mi)
                af[mi] = *(const bf16x8*)
                    &As[cur][(wm + mi * 16 + l16) * 64 + (((ks * 4 + quad) ^ swr) * 8)];
            __builtin_amdgcn_s_setprio(1);
#pragma unroll
            for (int mi = 0; mi < 4; ++mi)
#pragma unroll
                for (int ni = 0; ni < 4; ++ni)
                    acc[mi][ni] = MFMA16x16x32(af[mi], bf[ni], acc[mi][ni]);
            __builtin_amdgcn_s_setprio(0);
        }
        cur = cur < 2 ? cur + 1 : 0;
    }
    asm volatile("s_waitcnt vmcnt(0)" ::: "memory");   // drain wrap loads

    // Epilogue. C/D layout: col = lane&15, row = quad*4 + reg  [m89-verified]
    int row0 = bm * 256 + wm;
    int col0 = bn * 128 + wn;
#pragma unroll
    for (int mi = 0; mi < 4; ++mi) {
#pragma unroll
        for (int ni = 0; ni < 4; ++ni) {
            int gn = col0 + ni * 16 + l16;
            float bv = bias[gn];
            f32x4 c = acc[mi][ni];
            int h = gn >> 6, dd = gn & 63;
            if (z < 2) {                 // RoPE epilogue (Q, K)
                float inv = exp2f(-(float)(dd >> 1) * 0.41524101186092029f);
#pragma unroll
                for (int rr = 0; rr < 4; ++rr) {
                    int gm = row0 + mi * 16 + quad * 4 + rr;
                    int s = gm & 1023, b = gm >> 10;
                    int p = ((s << 4) + h) & 1023;    // reference reshape quirk
                    float val = c[rr] + bv;
                    float partner = __shfl_xor(val, 1);
                    float sn, cs;
                    __sincosf((float)p * inv, &sn, &cs);
                    float res = (dd & 1) ? fmaf(partner, sn, val * cs)
                                         : fmaf(val, cs, -(partner * sn));
                    dst[((b * 16 + h) * 1024 + s) * 64 + dd] = f2bf(res);
                }
            } else {                     // V^T epilogue
                int gm0 = row0 + mi * 16 + quad * 4;
                int s0 = gm0 & 1023, b = gm0 >> 10;
                short4v pack;
#pragma unroll
                for (int rr = 0; rr < 4; ++rr) pack[rr] = f2bf(c[rr] + bv);
                *(short4v*)&dst[((b * 16 + h) * 64 + dd) * 1024 + s0] = pack;
            }
        }
    }
}

// ---------------------------------------------------------------------------
// O-projection GEMM: out[4096,1024] fp32 = obuf @ Wo^T + bo.
// Same 256Mx128N / wave 64x64 / 3-buffer counted-vmcnt structure as gemm_qkv.
// Grid 128 = 8 xcd x {bm:2, bn:8}.
// ---------------------------------------------------------------------------
__global__ __launch_bounds__(512) void gemm_o(const short* __restrict__ A,
                                              const short* __restrict__ Bt,
                                              const float* __restrict__ bias,
                                              float* __restrict__ dst) {
    __shared__ short As[3][256 * 64];
    __shared__ short Bs[3][128 * 64];
    const int K = 1024;
    int flat = blockIdx.x;
    int xcd = flat & 7, j = flat >> 3;   // j in [0,16)
    int bm = xcd * 2 + (j & 1);
    int bn = j >> 1;

    int tid = threadIdx.x;
    int wave = tid >> 6, lane = tid & 63;
    int quad = lane >> 4, l16 = lane & 15;
    int wm = (wave >> 1) * 64;
    int wn = (wave & 1) * 64;
    int swr = l16 & 7;

    f32x4 acc[4][4] = {};

    auto stage = [&](int b, int t) {
        int kb = t * 64;
#pragma unroll
        for (int jj = 0; jj < 4; ++jj) {
            int c = jj * 512 + tid;
            int row = c >> 3, sl = c & 7;
            gl_lds16(A + (bm * 256 + row) * K + kb + ((sl ^ (row & 7)) * 8),
                     &As[b][c * 8]);
        }
#pragma unroll
        for (int jj = 0; jj < 2; ++jj) {
            int c = jj * 512 + tid;
            int row = c >> 3, sl = c & 7;
            gl_lds16(Bt + (bn * 128 + row) * K + kb + ((sl ^ (row & 7)) * 8),
                     &Bs[b][c * 8]);
        }
    };

    stage(0, 0);
    stage(1, 1);

    int cur = 0;
    for (int t = 0; t < 16; ++t) {
        asm volatile("s_waitcnt vmcnt(6)" ::: "memory");
        __builtin_amdgcn_sched_barrier(0);
        __builtin_amdgcn_s_barrier();
        __builtin_amdgcn_sched_barrier(0);
        int pre = cur >= 1 ? cur - 1 : 2;
        stage(pre, (t + 2) & 15);
#pragma unroll
        for (int ks = 0; ks < 2; ++ks) {
            bf16x8 bf[4], af[4];
#pragma unroll
            for (int ni = 0; ni < 4; ++ni)
                bf[ni] = *(const bf16x8*)
                    &Bs[cur][(wn + ni * 16 + l16) * 64 + (((ks * 4 + quad) ^ swr) * 8)];
#pragma unroll
            for (int mi = 0; mi < 4; ++mi)
                af[mi] = *(const bf16x8*)
                    &As[cur][(wm + mi * 16 + l16) * 64 + (((ks * 4 + quad) ^ swr) * 8)];
            __builtin_amdgcn_s_setprio(1);
#pragma unroll
            for (int mi = 0; mi < 4; ++mi)
#pragma unroll
                for (int ni = 0; ni < 4; ++ni)
                    acc[mi][ni] = MFMA16x16x32(af[mi], bf[ni], acc[mi][ni]);
            __builtin_amdgcn_s_setprio(0);
        }
        cur = cur < 2 ? cur + 1 : 0;
    }
    asm volatile("s_waitcnt vmcnt(0)" ::: "memory");

    int row0 = bm * 256 + wm;
    int col0 = bn * 128 + wn;
#pragma unroll
    for (int mi = 0; mi < 4; ++mi) {
#pragma unroll
        for (int ni = 0; ni < 4; ++ni) {
            int gn = col0 + ni * 16 + l16;
            float bv = bias[gn];
            f32x4 c = acc[mi][ni];
#pragma unroll
            for (int rr = 0; rr < 4; ++rr) {
                int gm = row0 + mi * 16 + quad * 4 + rr;
                dst[gm * 1024 + gn] = c[rr] + bv;
            }
        }
    }
}

// ---------------------------------------------------------------------------
// Flash attention, 8-wave blocks (512 thr). Unchanged from R6-R8 (passing).
// Counted-vmcnt 3-buffer K/V pipeline; swapped QK^T (S^T), cvt_pk P-pack,
// per-lane lsum, K/V slot-XOR swizzles, T5 setprio, XCD-grouped bh,
// de-onlined softmax (scores bounded).
// ---------------------------------------------------------------------------
__global__ __launch_bounds__(512) void attn_kernel(const short* __restrict__ Qh,
                                                   const short* __restrict__ Kh,
                                                   const short* __restrict__ Vt,
                                                   short* __restrict__ O) {
    __shared__ short Ks[3][32 * 64];   // [key][dim], slot-swizzled ^ (row&7)
    __shared__ short Vs[3][64 * 32];   // [dim][key], slot-swizzled ^ ((r&3)^((r>>2)&3))
    __shared__ short Pl[8][16 * 40];   // per-wave P [qrow][key], padded rows
    int tid = threadIdx.x;
    int wave = tid >> 6, lane = tid & 63;
    int quad = lane >> 4, l16 = lane & 15;
    int bh = blockIdx.x & 63, qt = blockIdx.x >> 6;   // XCD-grouped by bh
    int qrow = qt * 128 + wave * 16;

    const short* Qp = Qh + (bh * 1024 + qrow) * 64;
    bf16x8 aq[2];                      // Q frag: B-operand (col=qrow on l16)
#pragma unroll
    for (int kh = 0; kh < 2; ++kh)
        aq[kh] = *(const bf16x8*)&Qp[l16 * 64 + kh * 32 + quad * 8];

    const short* Kp = Kh + bh * 1024 * 64;
    const short* Vp = Vt + bh * 64 * 1024;

    // staging: waves 0-3 stage K (256 chunks), waves 4-7 stage V (256 chunks)
    int ck = tid & 255;
    bool isV = tid >= 256;
    int krow = ck >> 3;                          // K: key row, 8 slots x 8 dims
    int vrow = ck >> 2;                          // V: dim row, 4 slots x 8 keys
    int ksrc = krow * 64 + (((ck & 7) ^ (krow & 7)) * 8);
    int vsrc = vrow * 1024 + ((((ck & 3) ^ (vrow & 3) ^ ((vrow >> 2) & 3)) & 3) * 8);

    int ksw  = l16 & 7;                          // read swizzle, rows g*16+l16
    int vswr = (l16 & 3) ^ ((l16 >> 2) & 3);     // read swizzle, rows t*16+l16

    float lsum = 0.f;                  // partial denom for qrow l16
    f32x4 oa[4] = {};

    // prologue: tiles 0 and 1 in flight (1 load/thread each)
    if (!isV) { gl_lds16(Kp + ksrc, &Ks[0][ck * 8]);
                gl_lds16(Kp + 32 * 64 + ksrc, &Ks[1][ck * 8]); }
    else      { gl_lds16(Vp + vsrc, &Vs[0][ck * 8]);
                gl_lds16(Vp + 32 + vsrc, &Vs[1][ck * 8]); }

    short* Pw = &Pl[wave][0];

    int cur = 0;
    for (int kb = 0; kb < 1024; kb += 32) {
        asm volatile("s_waitcnt vmcnt(1)" ::: "memory");   // tile t landed
        __builtin_amdgcn_sched_barrier(0);
        __builtin_amdgcn_s_barrier();                      // raw: no drain
        __builtin_amdgcn_sched_barrier(0);
        int pre = cur >= 1 ? cur - 1 : 2;                  // (cur+2)%3
        int kb2 = (kb + 64) & 1023;                        // wrap-harmless
        if (!isV) gl_lds16(Kp + kb2 * 64 + ksrc, &Ks[pre][ck * 8]);
        else      gl_lds16(Vp + kb2 + vsrc,      &Vs[pre][ck * 8]);

        // S^T = K.Q^T: per g-tile, C: row=key=quad*4+r (+g*16), col=qrow=l16
#pragma unroll
        for (int g = 0; g < 2; ++g) {
            f32x4 s = {};
            __builtin_amdgcn_s_setprio(1);
#pragma unroll
            for (int kh = 0; kh < 2; ++kh) {
                bf16x8 ak = *(const bf16x8*)
                    &Ks[cur][(g * 16 + l16) * 64 + (((kh * 4 + quad) ^ ksw) * 8)];
                s = MFMA16x16x32(ak, aq[kh], s);   // A=K, B=Q  -> S^T
            }
            __builtin_amdgcn_s_setprio(0);
            float p[4];
#pragma unroll
            for (int r = 0; r < 4; ++r) {
                // exp(s/8) = exp2(s * 0.125*log2e)
                p[r] = exp2f(s[r] * 0.18033688011112042f);
                lsum += p[r];
            }
            u32x2 w;
            w[0] = cvtpk(p[0], p[1]);
            w[1] = cvtpk(p[2], p[3]);
            // P[qrow=l16][keys g*16+quad*4 .. +3], one b64 write
            *(u32x2*)&Pw[l16 * 40 + g * 16 + quad * 4] = w;
        }

        // V frags early so their latency hides under the lgkm wait
        bf16x8 bv[4];
#pragma unroll
        for (int t = 0; t < 4; ++t)
            bv[t] = *(const bf16x8*)&Vs[cur][(t * 16 + l16) * 32 + ((quad ^ vswr) * 8)];

        asm volatile("s_waitcnt lgkmcnt(0)" ::: "memory");      // P visible
        bf16x8 ap = *(const bf16x8*)&Pw[l16 * 40 + quad * 8];

        __builtin_amdgcn_s_setprio(1);
#pragma unroll
        for (int t = 0; t < 4; ++t)
            oa[t] = MFMA16x16x32(ap, bv[t], oa[t]);
        __builtin_amdgcn_s_setprio(0);

        cur = cur < 2 ? cur + 1 : 0;
    }

    // full denom for qrow l16: reduce partials across the 4 quads
    lsum += __shfl_xor(lsum, 16);
    lsum += __shfl_xor(lsum, 32);
    // epilogue rows are qrow = quad*4+r -> fetch their denom from lane l16=quad*4+r
    float inv[4];
#pragma unroll
    for (int r = 0; r < 4; ++r)
        inv[r] = 1.0f / __shfl(lsum, (lane & 48) + ((lane >> 4) & 3) * 4 + r);

    int b = bh >> 4, h = bh & 15;
#pragma unroll
    for (int t = 0; t < 4; ++t)
#pragma unroll
        for (int r = 0; r < 4; ++r) {
            int s = qrow + quad * 4 + r;
            O[(b * 1024 + s) * 1024 + h * 64 + t * 16 + l16] = f2bf(oa[t][r] * inv[r]);
        }
}

// ---------------------------------------------------------------------------
// Buffers:
//   ws [0, 8M) qb          ws [8,16M) kbuf -> obuf    ws [16,24M) vb
//   ws [24,32M) Wt x4      ws [32,40M) vt  (batched path)
//   d_out: [0,8M) qh, [8,16M) kh (bf16 scratch), finally fp32 result.
// Fallback (ws < 40MB): vt aliases qb, V-proj runs as a separate launch.
// ---------------------------------------------------------------------------
extern "C" void kernel_launch(void* const* d_in, const int* in_sizes, int n_in,
                              void* d_out, int out_size, void* d_ws, size_t ws_size,
                              hipStream_t stream) {
    const float* q  = (const float*)d_in[0];
    const float* k  = (const float*)d_in[1];
    const float* v  = (const float*)d_in[2];
    const float* Wq = (const float*)d_in[3];
    const float* bq = (const float*)d_in[4];
    const float* Wk = (const float*)d_in[5];
    const float* bk = (const float*)d_in[6];
    const float* Wv = (const float*)d_in[7];
    const float* bv = (const float*)d_in[8];
    const float* Wo = (const float*)d_in[9];
    const float* bo = (const float*)d_in[10];

    short* qb   = (short*)d_ws;
    short* kbuf = qb + (4 << 20);
    short* vb   = kbuf + (4 << 20);
    short* wt   = vb + (4 << 20);       // wtq|wtk|wtv|wto
    short* wto  = wt + (3 << 20);
    short* obuf = kbuf;                  // reuse (dead after projections)

    short* qh  = (short*)d_out;
    short* kh  = qh + (4 << 20);
    float* out = (float*)d_out;

    bool batch3 = ws_size >= ((size_t)40 << 20);
    short* vt = batch3 ? qb + (16 << 20) : qb;   // own region vs qb-alias

    prep<<<4096, 256, 0, stream>>>(q, k, v, Wq, Wk, Wv, Wo, qb, wt);

    if (batch3) {
        // Q,K,V projections in ONE launch (384 blocks, 256x128 tiles).
        gemm_qkv<<<384, 512, 0, stream>>>(qb, kbuf, vb, wt, bq, bk, bv,
                                          qh, kh, vt, 0);
    } else {
        gemm_qkv<<<256, 512, 0, stream>>>(qb, kbuf, vb, wt, bq, bk, bv,
                                          qh, kh, vt, 0);
        gemm_qkv<<<128, 512, 0, stream>>>(qb, kbuf, vb, wt, bq, bk, bv,
                                          qh, kh, vt, 2);
    }

    attn_kernel<<<512, 512, 0, stream>>>(qh, kh, vt, obuf);

    gemm_o<<<128, 512, 0, stream>>>(obuf, wto, bo, out);
}

// Round 11
// 208.867 us; speedup vs baseline: 1.1010x; 1.1010x over previous
//
#include <hip/hip_runtime.h>

typedef __attribute__((ext_vector_type(8))) short bf16x8;
typedef __attribute__((ext_vector_type(4))) short short4v;
typedef __attribute__((ext_vector_type(4))) float f32x4;
typedef __attribute__((ext_vector_type(2))) unsigned u32x2;

#define MFMA16x16x32(a, b, c) __builtin_amdgcn_mfma_f32_16x16x32_bf16((a), (b), (c), 0, 0, 0)

__device__ __forceinline__ short f2bf(float f) {
    unsigned u = __builtin_bit_cast(unsigned, f);
    u += 0x7FFFu + ((u >> 16) & 1u);   // RNE
    return (short)(u >> 16);
}

// packed fp32x2 -> bf16x2 (RNE): D[15:0]=cvt(S0), D[31:16]=cvt(S1).
__device__ __forceinline__ unsigned cvtpk(float lo, float hi) {
    unsigned r;
    asm("v_cvt_pk_bf16_f32 %0, %1, %2" : "=v"(r) : "v"(lo), "v"(hi));
    return r;
}

// async global->LDS, 16B per lane. LDS dest: wave-uniform base + lane*16 [m104].
__device__ __forceinline__ void gl_lds16(const void* g, void* l) {
    __builtin_amdgcn_global_load_lds((__attribute__((address_space(1))) void*)g,
                                     (__attribute__((address_space(3))) void*)l,
                                     16, 0, 0);
}

// Convert 16 consecutive floats at p into two bf16x8 packs.
__device__ __forceinline__ void cvt16(const float* __restrict__ p, bf16x8& lo, bf16x8& hi) {
    f32x4 a = *(const f32x4*)(p);
    f32x4 b = *(const f32x4*)(p + 4);
    f32x4 c = *(const f32x4*)(p + 8);
    f32x4 d = *(const f32x4*)(p + 12);
#pragma unroll
    for (int i = 0; i < 4; ++i) {
        lo[i]     = f2bf(a[i]);
        lo[i + 4] = f2bf(b[i]);
        hi[i]     = f2bf(c[i]);
        hi[i + 4] = f2bf(d[i]);
    }
}

// ---------------------------------------------------------------------------
// prep: fused {cvt3 (blocks 0..3071)} + {transW4 (blocks 3072..4095)}.
// [R6 verbatim — ~roofline: 92MB traffic ≈ 14µs.]
// ---------------------------------------------------------------------------
__global__ __launch_bounds__(256) void prep(const float* __restrict__ q,
                                            const float* __restrict__ k,
                                            const float* __restrict__ v,
                                            const float* __restrict__ w0,
                                            const float* __restrict__ w1,
                                            const float* __restrict__ w2,
                                            const float* __restrict__ w3,
                                            short* __restrict__ y,
                                            short* __restrict__ wt) {
    __shared__ short t[64][80];
    int bid = blockIdx.x, tid = threadIdx.x;
    if (bid < 3072) {
        int sel = bid >> 10;
        const float* x = sel == 0 ? q : (sel == 1 ? k : v);
        short* yy = y + (size_t)sel * (1 << 22);
        int i = ((bid & 1023) * 256 + tid) * 16;
        bf16x8 lo, hi;
        cvt16(x + i, lo, hi);
        *(bf16x8*)(yy + i)     = lo;
        *(bf16x8*)(yy + i + 8) = hi;
        return;
    }
    int tz = bid - 3072;
    int z = tz >> 8, rem = tz & 255, bx = rem & 15, by = rem >> 4;
    const float* W = z == 0 ? w0 : (z == 1 ? w1 : (z == 2 ? w2 : w3));
    short* Wt = wt + (size_t)z * (1 << 20);
    int sr = tid >> 2, sc = (tid & 3) * 16;
    bf16x8 lo, hi;
    cvt16(W + (by * 64 + sr) * 1024 + bx * 64 + sc, lo, hi);
    *(bf16x8*)&t[sr][sc]     = lo;
    *(bf16x8*)&t[sr][sc + 8] = hi;
    __syncthreads();
    bf16x8 o0, o1;
#pragma unroll
    for (int i = 0; i < 8; ++i) {
        o0[i] = t[sc + i][sr];
        o1[i] = t[sc + 8 + i][sr];
    }
    short* dst = Wt + (bx * 64 + sr) * 1024 + by * 64 + sc;
    *(bf16x8*)(dst)     = o0;
    *(bf16x8*)(dst + 8) = o1;
}

// ---------------------------------------------------------------------------
// QKV projection GEMM [R6 VERBATIM — best-measured config, 47.2µs/QKV].
// Four structure rewrites (R7-R9) all regressed; R6 sits on the measured
// ~8.2 TB/s staging plateau. 128x128 tile, BK=64, 512 thr / 8 waves 2Mx4N,
// 3-buffer distance-2 counted-vmcnt: {vmcnt(4) -> raw barrier -> stage(t+2)
// -> ds_read+MFMA(t)}. T2 slot-XOR swizzle (conflicts=0), T5 setprio.
// ---------------------------------------------------------------------------
__global__ __launch_bounds__(512) void gemm_qkv(const short* __restrict__ A0,
                                                const short* __restrict__ A1,
                                                const short* __restrict__ A2,
                                                const short* __restrict__ wt,
                                                const float* __restrict__ b0,
                                                const float* __restrict__ b1,
                                                const float* __restrict__ b2,
                                                short* __restrict__ d0,
                                                short* __restrict__ d1,
                                                short* __restrict__ d2,
                                                int zoff) {
    __shared__ short As[3][128 * 64];   // 48 KB
    __shared__ short Bs[3][128 * 64];   // 48 KB
    const int K = 1024;
    int flat = blockIdx.x;
    int xcd = flat & 7, j = flat >> 3;
    int bm = xcd * 4 + (j & 3);          // 4 A-panels per XCD
    int bn = (j >> 2) & 7;
    int z  = zoff + (j >> 5);
    const short* A    = z == 0 ? A0 : (z == 1 ? A1 : A2);
    const short* Bt   = wt + (size_t)z * (1 << 20);
    const float* bias = z == 0 ? b0 : (z == 1 ? b1 : b2);
    short* dst        = z == 0 ? d0 : (z == 1 ? d1 : d2);

    int tid = threadIdx.x;
    int wave = tid >> 6, lane = tid & 63;
    int quad = lane >> 4, l16 = lane & 15;
    int wm = (wave >> 2) * 64, wn = (wave & 3) * 32;
    int swr = l16 & 7;                   // read-side slot swizzle

    f32x4 acc[4][2] = {};

    auto stage = [&](int b, int t) {
        int kb = t * 64;
#pragma unroll
        for (int jj = 0; jj < 2; ++jj) {   // A tile: 128x64 = 1024 16B chunks
            int c = jj * 512 + tid;
            int row = c >> 3, sl = c & 7;
            gl_lds16(A + (bm * 128 + row) * K + kb + ((sl ^ (row & 7)) * 8),
                     &As[b][c * 8]);
        }
#pragma unroll
        for (int jj = 0; jj < 2; ++jj) {   // B tile: 128x64 = 1024 chunks
            int c = jj * 512 + tid;
            int row = c >> 3, sl = c & 7;
            gl_lds16(Bt + (bn * 128 + row) * K + kb + ((sl ^ (row & 7)) * 8),
                     &Bs[b][c * 8]);
        }
    };

    stage(0, 0);                          // prologue: 2 tiles in flight
    stage(1, 1);

    int cur = 0;
    for (int t = 0; t < 16; ++t) {
        asm volatile("s_waitcnt vmcnt(4)" ::: "memory");   // tile t landed
        __builtin_amdgcn_sched_barrier(0);
        __builtin_amdgcn_s_barrier();     // raw: no vmcnt(0) drain
        __builtin_amdgcn_sched_barrier(0);
        int pre = cur >= 1 ? cur - 1 : 2; // (cur+2)%3
        stage(pre, (t + 2) & 15);         // wrap-harmless on last 2 iters
#pragma unroll
        for (int ks = 0; ks < 2; ++ks) {
            bf16x8 bf[2], af[4];
#pragma unroll
            for (int ni = 0; ni < 2; ++ni)
                bf[ni] = *(const bf16x8*)
                    &Bs[cur][(wn + ni * 16 + l16) * 64 + (((ks * 4 + quad) ^ swr) * 8)];
#pragma unroll
            for (int mi = 0; mi < 4; ++mi)
                af[mi] = *(const bf16x8*)
                    &As[cur][(wm + mi * 16 + l16) * 64 + (((ks * 4 + quad) ^ swr) * 8)];
            __builtin_amdgcn_s_setprio(1);
#pragma unroll
            for (int mi = 0; mi < 4; ++mi)
#pragma unroll
                for (int ni = 0; ni < 2; ++ni)
                    acc[mi][ni] = MFMA16x16x32(af[mi], bf[ni], acc[mi][ni]);
            __builtin_amdgcn_s_setprio(0);
        }
        cur = cur < 2 ? cur + 1 : 0;
    }

    // Epilogue. C/D layout: col = lane&15, row = quad*4 + reg  [m89-verified]
    int row0 = bm * 128 + wm;
    int col0 = bn * 128 + wn;
#pragma unroll
    for (int mi = 0; mi < 4; ++mi) {
#pragma unroll
        for (int ni = 0; ni < 2; ++ni) {
            int gn = col0 + ni * 16 + l16;
            float bv = bias[gn];
            f32x4 c = acc[mi][ni];
            int h = gn >> 6, dd = gn & 63;
            if (z < 2) {                 // RoPE epilogue (Q, K)
                float inv = exp2f(-(float)(dd >> 1) * 0.41524101186092029f);
#pragma unroll
                for (int r = 0; r < 4; ++r) {
                    int gm = row0 + mi * 16 + quad * 4 + r;
                    int s = gm & 1023, b = gm >> 10;
                    int p = ((s << 4) + h) & 1023;    // reference reshape quirk
                    float val = c[r] + bv;
                    float partner = __shfl_xor(val, 1);
                    float sn, cs;
                    __sincosf((float)p * inv, &sn, &cs);
                    float res = (dd & 1) ? fmaf(partner, sn, val * cs)
                                         : fmaf(val, cs, -(partner * sn));
                    dst[((b * 16 + h) * 1024 + s) * 64 + dd] = f2bf(res);
                }
            } else {                     // V^T epilogue
                int gm0 = row0 + mi * 16 + quad * 4;
                int s0 = gm0 & 1023, b = gm0 >> 10;
                short4v pack;
#pragma unroll
                for (int r = 0; r < 4; ++r) pack[r] = f2bf(c[r] + bv);
                *(short4v*)&dst[((b * 16 + h) * 64 + dd) * 1024 + s0] = pack;
            }
        }
    }
}

// ---------------------------------------------------------------------------
// O-projection GEMM [R6 VERBATIM]: out = obuf @ Wo^T + bo, fp32 epilogue.
// ---------------------------------------------------------------------------
__global__ __launch_bounds__(512) void gemm_o(const short* __restrict__ A,
                                              const short* __restrict__ Bt,
                                              const float* __restrict__ bias,
                                              float* __restrict__ dst) {
    __shared__ short As[3][128 * 64];
    __shared__ short Bs[3][128 * 64];
    const int K = 1024;
    int flat = blockIdx.x;
    int xcd = flat & 7, j = flat >> 3;
    int bm = xcd * 4 + (j & 3);
    int bn = (j >> 2) & 7;

    int tid = threadIdx.x;
    int wave = tid >> 6, lane = tid & 63;
    int quad = lane >> 4, l16 = lane & 15;
    int wm = (wave >> 2) * 64, wn = (wave & 3) * 32;
    int swr = l16 & 7;

    f32x4 acc[4][2] = {};

    auto stage = [&](int b, int t) {
        int kb = t * 64;
#pragma unroll
        for (int jj = 0; jj < 2; ++jj) {
            int c = jj * 512 + tid;
            int row = c >> 3, sl = c & 7;
            gl_lds16(A + (bm * 128 + row) * K + kb + ((sl ^ (row & 7)) * 8),
                     &As[b][c * 8]);
        }
#pragma unroll
        for (int jj = 0; jj < 2; ++jj) {
            int c = jj * 512 + tid;
            int row = c >> 3, sl = c & 7;
            gl_lds16(Bt + (bn * 128 + row) * K + kb + ((sl ^ (row & 7)) * 8),
                     &Bs[b][c * 8]);
        }
    };

    stage(0, 0);
    stage(1, 1);

    int cur = 0;
    for (int t = 0; t < 16; ++t) {
        asm volatile("s_waitcnt vmcnt(4)" ::: "memory");
        __builtin_amdgcn_sched_barrier(0);
        __builtin_amdgcn_s_barrier();
        __builtin_amdgcn_sched_barrier(0);
        int pre = cur >= 1 ? cur - 1 : 2;
        stage(pre, (t + 2) & 15);
#pragma unroll
        for (int ks = 0; ks < 2; ++ks) {
            bf16x8 bf[2], af[4];
#pragma unroll
            for (int ni = 0; ni < 2; ++ni)
                bf[ni] = *(const bf16x8*)
                    &Bs[cur][(wn + ni * 16 + l16) * 64 + (((ks * 4 + quad) ^ swr) * 8)];
#pragma unroll
            for (int mi = 0; mi < 4; ++mi)
                af[mi] = *(const bf16x8*)
                    &As[cur][(wm + mi * 16 + l16) * 64 + (((ks * 4 + quad) ^ swr) * 8)];
            __builtin_amdgcn_s_setprio(1);
#pragma unroll
            for (int mi = 0; mi < 4; ++mi)
#pragma unroll
                for (int ni = 0; ni < 2; ++ni)
                    acc[mi][ni] = MFMA16x16x32(af[mi], bf[ni], acc[mi][ni]);
            __builtin_amdgcn_s_setprio(0);
        }
        cur = cur < 2 ? cur + 1 : 0;
    }

    int row0 = bm * 128 + wm;
    int col0 = bn * 128 + wn;
#pragma unroll
    for (int mi = 0; mi < 4; ++mi) {
#pragma unroll
        for (int ni = 0; ni < 2; ++ni) {
            int gn = col0 + ni * 16 + l16;
            float bv = bias[gn];
            f32x4 c = acc[mi][ni];
#pragma unroll
            for (int r = 0; r < 4; ++r) {
                int gm = row0 + mi * 16 + quad * 4 + r;
                dst[gm * 1024 + gn] = c[r] + bv;
            }
        }
    }
}

// ---------------------------------------------------------------------------
// Flash attention, KVBLK=64. 8-wave blocks (512 thr), 512 blocks
// (qt 8 x bh 64, XCD-grouped by bh). Wave owns 16 qrows.
// vs R6's KVBLK=32: HALF the iterations (16) and barriers, DOUBLE the
// independent work per sync point (4 QK g-tiles, 16 parallel exps, 8 PV
// MFMAs) -> more ILP against the serial QK->exp->pack->lgkm->PV chain that
// bounds attn (VALU 50% / MfmaUtil 14% at R2).
// Layouts are the verified 32-key ones scaled x2:
//   Ks[3][64 key][64 dim], slot-swizzle ^(row&7)  (row&7 == l16&7: g*16%8=0)
//   Vs[3][64 dim][64 key], SAME swizzle (rows now 128B like Ks)
//   Pl[8][16 qrow][72 key-pad]  (144B rows -> 2-way max on b64/b128: free)
// Staging: 1 K-chunk + 1 V-chunk per thread per tile (tid: row=tid>>3,
// sl=tid&7, pre-swizzled source, linear LDS dest). 3-buffer distance-2,
// {vmcnt(2) -> raw barrier -> stage(t+2) -> compute(t)}; exit drain added.
// Swapped QK^T (S^T=MFMA(K,Q)), cvt_pk P-pack, per-lane lsum, T5 setprio,
// de-onlined softmax (scores bounded).
// ---------------------------------------------------------------------------
__global__ __launch_bounds__(512) void attn_kernel(const short* __restrict__ Qh,
                                                   const short* __restrict__ Kh,
                                                   const short* __restrict__ Vt,
                                                   short* __restrict__ O) {
    __shared__ short Ks[3][64 * 64];   // 24 KB
    __shared__ short Vs[3][64 * 64];   // 24 KB
    __shared__ short Pl[8][16 * 72];   // 18 KB
    int tid = threadIdx.x;
    int wave = tid >> 6, lane = tid & 63;
    int quad = lane >> 4, l16 = lane & 15;
    int bh = blockIdx.x & 63, qt = blockIdx.x >> 6;   // XCD-grouped by bh
    int qrow = qt * 128 + wave * 16;

    const short* Qp = Qh + (bh * 1024 + qrow) * 64;
    bf16x8 aq[2];                      // Q frag: B-operand (col=qrow on l16)
#pragma unroll
    for (int kh = 0; kh < 2; ++kh)
        aq[kh] = *(const bf16x8*)&Qp[l16 * 64 + kh * 32 + quad * 8];

    const short* Kp = Kh + bh * 1024 * 64;
    const short* Vp = Vt + bh * 64 * 1024;

    // per-thread staging chunk: row=tid>>3 (64 rows), slot=tid&7 (x16B)
    int srow = tid >> 3, ssl = tid & 7;
    int ssw  = (ssl ^ (srow & 7)) * 8;             // pre-swizzled source slot
    int ksrc = srow * 64 + ssw;                    // K: [key][64 dims]
    int vsrc = srow * 1024 + ssw;                  // V: [dim][1024 keys]
    int rsw  = l16 & 7;                            // read-side slot swizzle

    float lsum = 0.f;                  // partial denom for qrow l16
    f32x4 oa[4] = {};

    // prologue: tiles 0 and 1 in flight (2 loads/thread each)
    gl_lds16(Kp + ksrc,            &Ks[0][tid * 8]);
    gl_lds16(Vp + vsrc,            &Vs[0][tid * 8]);
    gl_lds16(Kp + 64 * 64 + ksrc,  &Ks[1][tid * 8]);
    gl_lds16(Vp + 64 + vsrc,       &Vs[1][tid * 8]);

    short* Pw = &Pl[wave][0];

    int cur = 0;
    for (int kb = 0; kb < 1024; kb += 64) {
        asm volatile("s_waitcnt vmcnt(2)" ::: "memory");   // tile t landed
        __builtin_amdgcn_sched_barrier(0);
        __builtin_amdgcn_s_barrier();                      // raw: no drain
        __builtin_amdgcn_sched_barrier(0);
        int pre = cur >= 1 ? cur - 1 : 2;                  // (cur+2)%3
        int kb2 = (kb + 128) & 1023;                       // wrap-harmless
        gl_lds16(Kp + kb2 * 64 + ksrc, &Ks[pre][tid * 8]);
        gl_lds16(Vp + kb2 + vsrc,      &Vs[pre][tid * 8]);

        // S^T = K.Q^T: 4 g-tiles of 16 keys; C: row=key=quad*4+r(+g*16),
        // col=qrow=l16. Pack P[qrow=l16][key] via cvt_pk, one b64/g.
#pragma unroll
        for (int g = 0; g < 4; ++g) {
            f32x4 s = {};
            __builtin_amdgcn_s_setprio(1);
#pragma unroll
            for (int kh = 0; kh < 2; ++kh) {
                bf16x8 ak = *(const bf16x8*)
                    &Ks[cur][(g * 16 + l16) * 64 + (((kh * 4 + quad) ^ rsw) * 8)];
                s = MFMA16x16x32(ak, aq[kh], s);   // A=K, B=Q  -> S^T
            }
            __builtin_amdgcn_s_setprio(0);
            float p[4];
#pragma unroll
            for (int r = 0; r < 4; ++r) {
                // exp(s/8) = exp2(s * 0.125*log2e)
                p[r] = exp2f(s[r] * 0.18033688011112042f);
                lsum += p[r];
            }
            u32x2 w;
            w[0] = cvtpk(p[0], p[1]);
            w[1] = cvtpk(p[2], p[3]);
            *(u32x2*)&Pw[l16 * 72 + g * 16 + quad * 4] = w;
        }

        // V frags early so their latency hides under the lgkm wait
        bf16x8 bv0[4], bv1[4];
#pragma unroll
        for (int t = 0; t < 4; ++t) {
            bv0[t] = *(const bf16x8*)&Vs[cur][(t * 16 + l16) * 64 + ((quad ^ rsw) * 8)];
            bv1[t] = *(const bf16x8*)&Vs[cur][(t * 16 + l16) * 64 + (((4 + quad) ^ rsw) * 8)];
        }

        asm volatile("s_waitcnt lgkmcnt(0)" ::: "memory");      // P visible
        bf16x8 ap0 = *(const bf16x8*)&Pw[l16 * 72 + quad * 8];        // keys 0-31
        bf16x8 ap1 = *(const bf16x8*)&Pw[l16 * 72 + 32 + quad * 8];   // keys 32-63

        __builtin_amdgcn_s_setprio(1);
#pragma unroll
        for (int t = 0; t < 4; ++t) {
            oa[t] = MFMA16x16x32(ap0, bv0[t], oa[t]);
            oa[t] = MFMA16x16x32(ap1, bv1[t], oa[t]);
        }
        __builtin_amdgcn_s_setprio(0);

        cur = cur < 2 ? cur + 1 : 0;
    }
    asm volatile("s_waitcnt vmcnt(0)" ::: "memory");   // drain wrap loads

    // full denom for qrow l16: reduce partials across the 4 quads
    lsum += __shfl_xor(lsum, 16);
    lsum += __shfl_xor(lsum, 32);
    // epilogue rows are qrow = quad*4+r -> fetch denom from lane l16=quad*4+r
    float inv[4];
#pragma unroll
    for (int r = 0; r < 4; ++r)
        inv[r] = 1.0f / __shfl(lsum, (lane & 48) + ((lane >> 4) & 3) * 4 + r);

    int b = bh >> 4, h = bh & 15;
#pragma unroll
    for (int t = 0; t < 4; ++t)
#pragma unroll
        for (int r = 0; r < 4; ++r) {
            int s = qrow + quad * 4 + r;
            O[(b * 1024 + s) * 1024 + h * 64 + t * 16 + l16] = f2bf(oa[t][r] * inv[r]);
        }
}

// ---------------------------------------------------------------------------
// Buffers:
//   ws [0, 8M) qb          ws [8,16M) kbuf -> obuf    ws [16,24M) vb
//   ws [24,32M) Wt x4      ws [32,40M) vt  (batched path)
//   d_out: [0,8M) qh, [8,16M) kh (bf16 scratch), finally fp32 result.
// Fallback (ws < 40MB): vt aliases qb, V-proj runs as a separate launch.
// ---------------------------------------------------------------------------
extern "C" void kernel_launch(void* const* d_in, const int* in_sizes, int n_in,
                              void* d_out, int out_size, void* d_ws, size_t ws_size,
                              hipStream_t stream) {
    const float* q  = (const float*)d_in[0];
    const float* k  = (const float*)d_in[1];
    const float* v  = (const float*)d_in[2];
    const float* Wq = (const float*)d_in[3];
    const float* bq = (const float*)d_in[4];
    const float* Wk = (const float*)d_in[5];
    const float* bk = (const float*)d_in[6];
    const float* Wv = (const float*)d_in[7];
    const float* bv = (const float*)d_in[8];
    const float* Wo = (const float*)d_in[9];
    const float* bo = (const float*)d_in[10];

    short* qb   = (short*)d_ws;
    short* kbuf = qb + (4 << 20);
    short* vb   = kbuf + (4 << 20);
    short* wt   = vb + (4 << 20);       // wtq|wtk|wtv|wto
    short* wto  = wt + (3 << 20);
    short* obuf = kbuf;                  // reuse (dead after projections)

    short* qh  = (short*)d_out;
    short* kh  = qh + (4 << 20);
    float* out = (float*)d_out;

    bool batch3 = ws_size >= ((size_t)40 << 20);
    short* vt = batch3 ? qb + (16 << 20) : qb;   // own region vs qb-alias

    prep<<<4096, 256, 0, stream>>>(q, k, v, Wq, Wk, Wv, Wo, qb, wt);

    if (batch3) {
        // Q,K,V projections in ONE launch (768 blocks, z = j>>5).
        gemm_qkv<<<768, 512, 0, stream>>>(qb, kbuf, vb, wt, bq, bk, bv,
                                          qh, kh, vt, 0);
    } else {
        gemm_qkv<<<512, 512, 0, stream>>>(qb, kbuf, vb, wt, bq, bk, bv,
                                          qh, kh, vt, 0);
        gemm_qkv<<<256, 512, 0, stream>>>(qb, kbuf, vb, wt, bq, bk, bv,
                                          qh, kh, vt, 2);
    }

    attn_kernel<<<512, 512, 0, stream>>>(qh, kh, vt, obuf);

    gemm_o<<<256, 512, 0, stream>>>(obuf, wto, bo, out);
}